// Round 9
// baseline (372.208 us; speedup 1.0000x reference)
//
#include <hip/hip_runtime.h>
#include <type_traits>
#include <utility>

// ---------------- problem constants ----------------
#define B_    8
#define NQ_   1024
#define I_    21760      // 128*128 + 64*64 + 32*32 + 16*16
#define EMB_  256
#define HID_  256
#define H_    8
#define CH_   32

typedef float  f32x4  __attribute__((ext_vector_type(4)));
typedef __bf16 bf16x8 __attribute__((ext_vector_type(8)));
typedef short  s16x8  __attribute__((ext_vector_type(8)));

// ---- MFMA shim: works whether the builtin wants v8bf16 or v8i16 ----
template <typename V, typename = void>
struct bf16_mfma_native : std::false_type {};
template <typename V>
struct bf16_mfma_native<V, std::void_t<decltype(__builtin_amdgcn_mfma_f32_16x16x32_bf16(
    std::declval<V>(), std::declval<V>(), std::declval<f32x4>(), 0, 0, 0))>>
    : std::true_type {};

template <typename V>
__device__ __forceinline__ f32x4 mfma_dispatch(V a, V b, f32x4 c) {
  if constexpr (bf16_mfma_native<V>::value) {
    return __builtin_amdgcn_mfma_f32_16x16x32_bf16(a, b, c, 0, 0, 0);
  } else {
    return __builtin_amdgcn_mfma_f32_16x16x32_bf16(
        __builtin_bit_cast(s16x8, a), __builtin_bit_cast(s16x8, b), c, 0, 0, 0);
  }
}

__device__ __forceinline__ f32x4 MFMA(s16x8 a, s16x8 b, f32x4 c) {
  return mfma_dispatch(__builtin_bit_cast(bf16x8, a), __builtin_bit_cast(bf16x8, b), c);
}

// float -> bf16 bits, round-to-nearest-even
__device__ __forceinline__ unsigned short f2bf(float f) {
  unsigned u = __float_as_uint(f);
  u += 0x7fffu + ((u >> 16) & 1u);
  return (unsigned short)(u >> 16);
}

// pack 4 floats -> s16x8 half (helper for staging)
__device__ __forceinline__ void pack4(s16x8& p, int o, float4 v) {
  p[o + 0] = (short)f2bf(v.x); p[o + 1] = (short)f2bf(v.y);
  p[o + 2] = (short)f2bf(v.z); p[o + 3] = (short)f2bf(v.w);
}

// ---------------------------------------------------------------
// convert_w: W (fp32 row-major [k][col]) -> bf16 col-major [col][k]
// (fragment-ready: 16 B per MFMA B-frag contiguous in k).
// 114688 uints total: wib 32768, wqb 49152, wob 32768.
// ---------------------------------------------------------------
__global__ __launch_bounds__(512) void convert_w(
    const float* __restrict__ Wi, const float* __restrict__ Wq,
    const float* __restrict__ Wo, unsigned* __restrict__ wib,
    unsigned* __restrict__ wqb, unsigned* __restrict__ wob) {
  const int g = blockIdx.x * 512 + threadIdx.x;   // 0..114687
  const float* S;
  unsigned* D;
  int N, t;
  if (g < 32768)      { S = Wi; D = wib; N = 256; t = g; }
  else if (g < 81920) { S = Wq; D = wqb; N = 384; t = g - 32768; }
  else                { S = Wo; D = wob; N = 256; t = g - 81920; }
  const int col = t >> 7, k = (t & 127) << 1;
  const unsigned lo = f2bf(S[(size_t)k * N + col]);
  const unsigned hi = f2bf(S[(size_t)(k + 1) * N + col]);
  D[t] = lo | (hi << 16);
}

// ---------------------------------------------------------------
// GEMM phase, BM=64, K fixed = 256:  Out[M,N] = A[M,256] @ W + bias
// 512 threads = 8 waves. Wave w owns columns {st*128 + w*16 .. +15}.
// W fragments streamed per k-step from the bf16 col-major table Wb
// (L2-resident, 16 B contiguous per frag); each frag reused by 4
// row-tiles (64 MFMAs/wave/tile vs 32 at BM=32 -> overhead halves).
// SINGLE 64x256 LDS buffer (row stride 264, 33792 B -- the 2x64 dbuf
// at 67.5 KB exceeded the 64 KiB per-workgroup LDS launch limit and
// killed the container during graph capture). Two-barrier loop (r4
// structure): pack(t) -> sync -> issue loads(t+1) -> compute(t) ->
// stores(t) -> sync. r5's A/B showed dbuf ~= single at BM=32.
// OUTM: 0 = fp32 linear [M][N], 1 = bf16 head-major [(b*8+h)][i][32]
// ---------------------------------------------------------------
template <int NS, int OUTM>
__device__ __forceinline__ void gemm_phase(
    const float* __restrict__ A, const unsigned short* __restrict__ Wb,
    const float* __restrict__ bias, void* __restrict__ Out,
    const int N, const int Mtiles, short* __restrict__ lds,
    const int bid0, const int nblk) {
  const int tid  = threadIdx.x;
  const int lane = tid & 63;
  const int wave = tid >> 6;
  const int quad = lane >> 4;
  const int ln   = lane & 15;

  float bv[NS];
#pragma unroll
  for (int st = 0; st < NS; ++st) bv[st] = bias[st * 128 + wave * 16 + ln];

  // per-thread W-frag base (k advances with ks inside the loop)
  const unsigned short* wbase = Wb + (size_t)(wave * 16 + ln) * 256 + quad * 8;

  const int sr = tid >> 3;          // staging row 0..63
  const int sc = (tid & 7) * 32;    // staging col (32 floats per thread)

  int t = bid0;
  if (t >= Mtiles) { return; }

  float4 v0, v1, v2, v3, v4, v5, v6, v7;
  // --- prologue: load tile t into registers ---
  {
    const float4* src = (const float4*)(A + ((size_t)t * 64 + sr) * 256 + sc);
    v0 = src[0]; v1 = src[1]; v2 = src[2]; v3 = src[3];
    v4 = src[4]; v5 = src[5]; v6 = src[6]; v7 = src[7];
  }

  for (; t < Mtiles; t += nblk) {
    // --- pack registers (tile t) fp32 -> bf16 into LDS ---
    {
      s16x8 p0, p1, p2, p3;
      pack4(p0, 0, v0); pack4(p0, 4, v1);
      pack4(p1, 0, v2); pack4(p1, 4, v3);
      pack4(p2, 0, v4); pack4(p2, 4, v5);
      pack4(p3, 0, v6); pack4(p3, 4, v7);
      *(s16x8*)&lds[sr * 264 + sc]      = p0;
      *(s16x8*)&lds[sr * 264 + sc + 8]  = p1;
      *(s16x8*)&lds[sr * 264 + sc + 16] = p2;
      *(s16x8*)&lds[sr * 264 + sc + 24] = p3;
    }
    __syncthreads();

    // --- issue next tile's loads NOW; they fly under the compute ---
    const int tn = t + nblk;
    if (tn < Mtiles) {
      const float4* src = (const float4*)(A + ((size_t)tn * 64 + sr) * 256 + sc);
      v0 = src[0]; v1 = src[1]; v2 = src[2]; v3 = src[3];
      v4 = src[4]; v5 = src[5]; v6 = src[6]; v7 = src[7];
    }

    // --- compute tile t; W frags streamed from L2 ---
    f32x4 acc[NS][4];
#pragma unroll
    for (int st = 0; st < NS; ++st)
#pragma unroll
      for (int rt = 0; rt < 4; ++rt)
        acc[st][rt] = f32x4{bv[st], bv[st], bv[st], bv[st]};
#pragma unroll
    for (int ks = 0; ks < 8; ++ks) {
      s16x8 a0 = *(const s16x8*)&lds[ln * 264 + ks * 32 + quad * 8];
      s16x8 a1 = *(const s16x8*)&lds[(ln + 16) * 264 + ks * 32 + quad * 8];
      s16x8 a2 = *(const s16x8*)&lds[(ln + 32) * 264 + ks * 32 + quad * 8];
      s16x8 a3 = *(const s16x8*)&lds[(ln + 48) * 264 + ks * 32 + quad * 8];
#pragma unroll
      for (int st = 0; st < NS; ++st) {
        const s16x8 wf = *(const s16x8*)&wbase[(size_t)st * 128 * 256 + ks * 32];
        acc[st][0] = MFMA(a0, wf, acc[st][0]);
        acc[st][1] = MFMA(a1, wf, acc[st][1]);
        acc[st][2] = MFMA(a2, wf, acc[st][2]);
        acc[st][3] = MFMA(a3, wf, acc[st][3]);
      }
    }

    // --- epilogue stores for tile t ---
    const size_t rowBase = (size_t)t * 64;
    if constexpr (OUTM == 1) {
      // bf16 head-major: [(b*8 + h)][i][32]; tiles never cross b (I_%64==0)
      const int tb  = (int)(rowBase / I_);
      const int ir0 = (int)(rowBase - (size_t)tb * I_);
      unsigned short* O = (unsigned short*)Out;
#pragma unroll
      for (int st = 0; st < NS; ++st) {
        const int ng = st * 128 + wave * 16 + ln;
        const int hh = ng >> 5, cc = ng & 31;
        const size_t pl = (size_t)(tb * 8 + hh) * I_;
#pragma unroll
        for (int rt = 0; rt < 4; ++rt) {
#pragma unroll
          for (int r = 0; r < 4; ++r) {
            const size_t i = pl + (size_t)(ir0 + rt * 16 + quad * 4 + r);
            O[i * 32 + cc] = f2bf(acc[st][rt][r]);
          }
        }
      }
    } else {
      float* O = (float*)Out;
#pragma unroll
      for (int st = 0; st < NS; ++st) {
        const int ng = st * 128 + wave * 16 + ln;
#pragma unroll
        for (int rt = 0; rt < 4; ++rt) {
#pragma unroll
          for (int r = 0; r < 4; ++r) {
            const size_t m = rowBase + rt * 16 + quad * 4 + r;
            O[m * N + ng] = acc[st][rt][r];
          }
        }
      }
    }
    __syncthreads();   // protect LDS before next pack
  }
}

// ---------------------------------------------------------------
// Launch 2: grid 512 -> 2 resident blocks per CU (VGPR-bound class).
// Blocks 0..447: img GEMM (2720 tiles of 64 rows, stride 448).
// Blocks 448..511: queries GEMM (128 tiles, stride 64).
// ---------------------------------------------------------------
__global__ __launch_bounds__(512, 4) void proj_kernel(
    const float* __restrict__ img, const float* __restrict__ queries,
    const unsigned short* __restrict__ wib, const float* __restrict__ b_img,
    const unsigned short* __restrict__ wqb, const float* __restrict__ b_q,
    unsigned short* __restrict__ imgp, float* __restrict__ qp) {
  __shared__ __align__(16) short lds[64 * 264];   // 33792 B (<= 64 KiB limit)
  if (blockIdx.x < 448) {
    gemm_phase<2, 1>(img, wib, b_img, (void*)imgp, 256, (B_ * I_) / 64,
                     lds, blockIdx.x, 448);
  } else {
    gemm_phase<3, 0>(queries, wqb, b_q, (void*)qp, 384, (B_ * NQ_) / 64,
                     lds, (int)blockIdx.x - 448, 64);
  }
}

// ---------------------------------------------------------------
// Launch 3: fused softmax + sampling + bilinear gather + output GEMM.
// Block = (batch b, 16 queries, all 8 heads); 256 threads; grid 512.
// Batch-per-XCD: b = blk & 7 (hw round-robin) keeps each XCD's L2 on
// one batch's 11 MB pyramid.
// Per half (8 queries):
//   Phase A (4 iters): item=(q8*8+h)*16+lp -> 16-wide softmax via
//     shfl_xor, fold 4 bilinear corners into 2 contiguous x-PAIRS
//     (head-major imgp: pair = 128 B) -> LDS weights + bases.
//   Phase B (4 iters): item=(q8*8+h)*16+c2; p=c2>>3 picks the pair
//     element, 8 threads cover a 64 B pixel slice with uint2 loads;
//     shfl_xor(8) combines pair halves; result written as 2 bf16 into
//     the 16x264 LDS A-tile (row = query, col = h*32+ch).
// Epilogue: out[16x256] = A @ W_out + b_out via 32 MFMAs; W fragments
// read 16 B-contiguous from wob (L2-hot), so no W register residency.
// ---------------------------------------------------------------
__global__ __launch_bounds__(256) void msda_out_kernel(
    const unsigned int* __restrict__ imgp,  // bf16 pairs, head-major [(b*8+h)*I_][16] uints
    const float* __restrict__ qp, const float* __restrict__ refp,
    const unsigned short* __restrict__ wob, const float* __restrict__ b_out,
    float* __restrict__ out) {
  __shared__ __align__(16) float sw[1024][4];   // 16 KB
  __shared__ __align__(16) int   sib[1024][2];  //  8 KB
  __shared__ __align__(16) short lA[16 * 264];  //  8.25 KB
  const int blk = blockIdx.x;
  const int b   = blk & 7;        // batch-per-XCD
  const int n0  = (blk >> 3) << 4;  // first of 16 queries
  const int tid = threadIdx.x;

  for (int half = 0; half < 2; ++half) {
    // ---------------- phase A ----------------
#pragma unroll
    for (int it = 0; it < 4; ++it) {
      const int item = it * 256 + tid;
      const int lp = item & 15, gh = item >> 4;    // gh = q8*8 + h
      const int q8 = gh >> 3, h = gh & 7;
      const int l = lp >> 2;
      const int ww = 128 >> l;                              // square levels
      const int start = (65536 - (65536 >> (2 * l))) / 3;   // 0,16384,20480,21504
      const float invsh = __uint_as_float((unsigned)(120 + l) << 23);  // 1/ww exactly

      const int n   = n0 + (half << 3) + q8;
      const int bid = (b << 10) | n;
      const float* qb = qp + (size_t)bid * 384 + h * 48 + lp * 3;
      const float ox = qb[0], oy = qb[1], z = qb[2];
      // softmax over the 16 lanes of this (q,h) group
      float m = z;
      m = fmaxf(m, __shfl_xor(m, 1, 16));
      m = fmaxf(m, __shfl_xor(m, 2, 16));
      m = fmaxf(m, __shfl_xor(m, 4, 16));
      m = fmaxf(m, __shfl_xor(m, 8, 16));
      float e = __expf(z - m);
      float s = e;
      s += __shfl_xor(s, 1, 16);
      s += __shfl_xor(s, 2, 16);
      s += __shfl_xor(s, 4, 16);
      s += __shfl_xor(s, 8, 16);
      const float a = e / s;

      const float rx = refp[bid * 2], ry = refp[bid * 2 + 1];
      const float px = (rx + ox * invsh) * (float)ww - 0.5f;
      const float py = (ry + oy * invsh) * (float)ww - 0.5f;
      const float x0f = floorf(px), y0f = floorf(py);
      const float wx = px - x0f, wy = py - y0f;
      const int x0 = (int)x0f, y0 = (int)y0f;

      // fold x-corners onto the contiguous pair (xb, xb+1)
      const int xb = min(max(x0, 0), ww - 2);
      float u0 = 0.f, u1 = 0.f;
      if (x0 >= 0 && x0 < ww)         { if (x0 == xb)     u0 += 1.f - wx; else u1 += 1.f - wx; }
      if (x0 + 1 >= 0 && x0 + 1 < ww) { if (x0 + 1 == xb) u0 += wx;       else u1 += wx; }
      const float wy0 = (y0 >= 0     && y0 < ww)     ? a * (1.f - wy) : 0.f;
      const float wy1 = (y0 + 1 >= 0 && y0 + 1 < ww) ? a * wy         : 0.f;
      const int yc0 = min(max(y0, 0), ww - 1);
      const int yc1 = min(max(y0 + 1, 0), ww - 1);

      const int pb = (b * 8 + h) * I_ + start + xb;
      sw[item][0] = wy0 * u0; sw[item][1] = wy0 * u1;
      sw[item][2] = wy1 * u0; sw[item][3] = wy1 * u1;
      sib[item][0] = (pb + yc0 * ww) * 16;   // uint (bf16-pair) units
      sib[item][1] = (pb + yc1 * ww) * 16;
    }
    __syncthreads();

    // ---------------- phase B ----------------
#pragma unroll
    for (int it = 0; it < 4; ++it) {
      const int item = it * 256 + tid;
      const int c2 = item & 15, gh = item >> 4;
      const int q8 = gh >> 3, h = gh & 7;
      const int p  = c2 >> 3;                    // which pixel of the x-pair
      const int cp = ((c2 & 7) << 1) + (p << 4); // uint offset: pair element + channel pair
      float a0 = 0.f, a1 = 0.f, a2 = 0.f, a3 = 0.f;
#pragma unroll
      for (int lp = 0; lp < 16; ++lp) {
        const float4 w4 = *(const float4*)sw[gh * 16 + lp];   // LDS broadcast
        const int2   ib = *(const int2*)sib[gh * 16 + lp];
        const float w0 = p ? w4.y : w4.x;   // row y0 weight for my pixel
        const float w1 = p ? w4.w : w4.z;   // row y1 weight for my pixel
        const uint2 ua = *(const uint2*)&imgp[ib.x + cp];
        const uint2 ub = *(const uint2*)&imgp[ib.y + cp];
        a0 += w0 * __uint_as_float(ua.x << 16);
        a1 += w0 * __uint_as_float(ua.x & 0xffff0000u);
        a2 += w0 * __uint_as_float(ua.y << 16);
        a3 += w0 * __uint_as_float(ua.y & 0xffff0000u);
        a0 += w1 * __uint_as_float(ub.x << 16);
        a1 += w1 * __uint_as_float(ub.x & 0xffff0000u);
        a2 += w1 * __uint_as_float(ub.y << 16);
        a3 += w1 * __uint_as_float(ub.y & 0xffff0000u);
      }
      // combine the two halves of the x-pair (lanes tid and tid^8: same gh)
      a0 += __shfl_xor(a0, 8);
      a1 += __shfl_xor(a1, 8);
      a2 += __shfl_xor(a2, 8);
      a3 += __shfl_xor(a3, 8);
      const float rx = p ? a2 : a0;
      const float ry = p ? a3 : a1;
      // write 2 bf16 channels into the A-tile: row = query, col = h*32+ch
      const int row = (half << 3) + q8;
      const unsigned pr = (unsigned)f2bf(rx) | ((unsigned)f2bf(ry) << 16);
      *(unsigned*)&lA[row * 264 + h * 32 + ((c2 & 7) << 2) + (p << 1)] = pr;
    }
    __syncthreads();
  }

  // ---------------- MFMA epilogue: out = A @ W_out + b_out ----------------
  const int lane = tid & 63, wv = tid >> 6;   // 4 waves
  const int quad = lane >> 4, ln = lane & 15;
  f32x4 acc[4];
#pragma unroll
  for (int s = 0; s < 4; ++s) {
    const float bb = b_out[wv * 64 + s * 16 + ln];
    acc[s] = f32x4{bb, bb, bb, bb};
  }
#pragma unroll
  for (int ks = 0; ks < 8; ++ks) {
    const s16x8 a = *(const s16x8*)&lA[ln * 264 + ks * 32 + quad * 8];
#pragma unroll
    for (int s = 0; s < 4; ++s) {
      const int ng = wv * 64 + s * 16 + ln;
      const s16x8 wf = *(const s16x8*)&wob[(size_t)ng * 256 + ks * 32 + quad * 8];
      acc[s] = MFMA(a, wf, acc[s]);
    }
  }
#pragma unroll
  for (int s = 0; s < 4; ++s) {
    const int ng = wv * 64 + s * 16 + ln;
#pragma unroll
    for (int r = 0; r < 4; ++r) {
      const int m = quad * 4 + r;   // query row 0..15
      out[(size_t)(b * 1024 + n0 + m) * 256 + ng] = acc[s][r];
    }
  }
}

// ---------------------------------------------------------------
// workspace layout (bytes)
// ---------------------------------------------------------------
#define OFF_IMGP 0ULL                        // 8*8*21760*32*2 = 89,128,960 (bf16, head-major)
#define OFF_QP   89128960ULL                 // 8192*384*4     = 12,582,912
#define OFF_WIB  101711872ULL                // 256*256*2      =    131,072 (bf16 col-major W_img)
#define OFF_WQB  101842944ULL                // 384*256*2      =    196,608 (bf16 col-major W_q)
#define OFF_WOB  102039552ULL                // 256*256*2      =    131,072 (bf16 col-major W_out)
#define WS_NEEDED 102170624ULL

extern "C" void kernel_launch(void* const* d_in, const int* in_sizes, int n_in,
                              void* d_out, int out_size, void* d_ws, size_t ws_size,
                              hipStream_t stream) {
  const float* img     = (const float*)d_in[0];
  const float* queries = (const float*)d_in[2];
  const float* refp    = (const float*)d_in[3];
  const float* W_img   = (const float*)d_in[4];
  const float* b_img   = (const float*)d_in[5];
  const float* W_q     = (const float*)d_in[6];
  const float* b_q     = (const float*)d_in[7];
  const float* W_out   = (const float*)d_in[8];
  const float* b_out   = (const float*)d_in[9];

  if (ws_size < WS_NEEDED) return;  // workspace too small -> fail loudly

  char* ws = (char*)d_ws;
  unsigned short* imgp = (unsigned short*)(ws + OFF_IMGP);
  float* qp            = (float*)(ws + OFF_QP);
  unsigned short* wib  = (unsigned short*)(ws + OFF_WIB);
  unsigned short* wqb  = (unsigned short*)(ws + OFF_WQB);
  unsigned short* wob  = (unsigned short*)(ws + OFF_WOB);

  // launch 1: W matrices -> bf16 col-major fragment tables (0.9 MB)
  hipLaunchKernelGGL(convert_w, dim3(224), dim3(512), 0, stream,
                     W_img, W_q, W_out,
                     (unsigned*)wib, (unsigned*)wqb, (unsigned*)wob);
  // launch 2: img proj (BM=64, single-buffer LDS) + queries proj
  hipLaunchKernelGGL(proj_kernel, dim3(512), dim3(512), 0, stream,
                     img, queries, wib, b_img, wqb, b_q, imgp, qp);
  // launch 3: fused softmax + sampling + gather + output GEMM
  hipLaunchKernelGGL(msda_out_kernel, dim3(512), dim3(256), 0, stream,
                     (const unsigned int*)imgp, qp, refp, wob, b_out,
                     (float*)d_out);
}